// Round 1
// baseline (670.892 us; speedup 1.0000x reference)
//
#include <hip/hip_runtime.h>

// Problem constants (from reference):
//   N = 512, DX = 1/511, DT = 1e-7, NUM_STEPS = 200 -> 199 output states
//   MB = 256 (material boundary column), interface column ii = 255
#define GN 512
#define GNN (GN * GN)
#define NSTEPS 199

// Precomputed coefficients (double -> float once):
//   c_diff = DT / DX^2 = 1e-7 * 511^2
//   c_adv  = DT / (2*DX) = 1e-7 * 511 / 2
//   c_rea  = DT
__constant__ const float kCdiff = (float)(1e-7 * 511.0 * 511.0); // 0.0261121
__constant__ const float kCadv  = (float)(1e-7 * 511.0 / 2.0);   // 2.5555e-5
__constant__ const float kCrea  = 1e-7f;

// One time step. Per-point closed form (verified against reference op order):
//   out(i,j) = inner(clamp(i,1,510), clamp(j,1,510))
// where inner(ic,jc) is:
//   jc==255 : (k1*T[ic,256] + k2*T[ic,254]) / (k1+k2)          (old T)
//   else    : Tc - DT*kap*(Tc^2*Tx - Tc*Ty) + DT*alp*(Txx+Tyy)
//             + DT*kap*(Tc^3 - Tc^2 + Tc)
//   with kap/alp = (jc<256) ? k1/alpha1 : k2/alpha2,
//   Tx,Txx along rows (axis 0), Ty,Tyy along cols (axis 1).
__global__ __launch_bounds__(256) void adr_step(
    const float* __restrict__ src, float* __restrict__ dst,
    const float* __restrict__ pk1, const float* __restrict__ pk2,
    const float* __restrict__ pa1, const float* __restrict__ pa2)
{
    const int tid = blockIdx.x * blockDim.x + threadIdx.x;
    const int i = tid >> 9;        // row
    const int j = tid & (GN - 1);  // col

    const int ic = min(max(i, 1), GN - 2);
    const int jc = min(max(j, 1), GN - 2);

    const float k1 = pk1[0];
    const float k2 = pk2[0];
    const float a1 = pa1[0];
    const float a2 = pa2[0];

    const float* rowp = src + ic * GN;
    const float tc = rowp[jc];
    const float tl = rowp[jc - 1];     // T[ic, jc-1]
    const float tr = rowp[jc + 1];     // T[ic, jc+1]
    const float tm = rowp[jc - GN];    // T[ic-1, jc]
    const float tp = rowp[jc + GN];    // T[ic+1, jc]

    float out;
    if (jc == 255) {
        // interface column: k_left = k_map[:,255] = k1, k_right = k_map[:,256] = k2
        out = (k1 * tr + k2 * tl) / (k1 + k2);
    } else {
        const float kap = (jc < 256) ? k1 : k2;
        const float alp = (jc < 256) ? a1 : a2;
        const float adv = kap * kCadv * (tc * tc * (tp - tm) - tc * (tr - tl));
        const float dif = alp * kCdiff * ((tm + tp + tl + tr) - 4.0f * tc);
        const float rea = kCrea * kap * ((tc * tc * tc - tc * tc) + tc);
        out = tc - adv + dif + rea;
    }

    dst[tid] = out;
}

extern "C" void kernel_launch(void* const* d_in, const int* in_sizes, int n_in,
                              void* d_out, int out_size, void* d_ws, size_t ws_size,
                              hipStream_t stream) {
    (void)in_sizes; (void)n_in; (void)out_size; (void)d_ws; (void)ws_size;

    const float* u0 = (const float*)d_in[0];
    const float* k1 = (const float*)d_in[1];
    const float* k2 = (const float*)d_in[2];
    const float* a1 = (const float*)d_in[3];
    const float* a2 = (const float*)d_in[4];
    float* out = (float*)d_out;

    dim3 block(256);
    dim3 grid(GNN / 256);

    const float* src = u0;
    for (int s = 0; s < NSTEPS; ++s) {
        float* dst = out + (size_t)s * GNN;
        adr_step<<<grid, block, 0, stream>>>(src, dst, k1, k2, a1, a2);
        src = dst;
    }
}